// Round 1
// baseline (823.407 us; speedup 1.0000x reference)
//
#include <hip/hip_runtime.h>

#define DIM 64

__global__ void coo_scatter_kernel(const float* __restrict__ user_emb,
                                   const float* __restrict__ entity_emb,
                                   const int* __restrict__ rows,
                                   const int* __restrict__ cols,
                                   const float* __restrict__ vals,
                                   float* __restrict__ entity_agg,
                                   float* __restrict__ user_agg,
                                   int nnz) {
    long long tid = (long long)blockIdx.x * blockDim.x + threadIdx.x;
    long long total = (long long)nnz * DIM;
    if (tid >= total) return;
    int edge = (int)(tid >> 6);   // wave-uniform: all 64 lanes share one edge
    int d = (int)(tid & 63);      // lane = dim -> coalesced gather/scatter
    int r = rows[edge];
    int c = cols[edge];
    float v = vals[edge];
    // entity_agg[c] += v * user_emb[r]
    atomicAdd(&entity_agg[c * DIM + d], v * user_emb[r * DIM + d]);
    // user_agg[r] += v * entity_emb[c]
    atomicAdd(&user_agg[r * DIM + d], v * entity_emb[c * DIM + d]);
}

extern "C" void kernel_launch(void* const* d_in, const int* in_sizes, int n_in,
                              void* d_out, int out_size, void* d_ws, size_t ws_size,
                              hipStream_t stream) {
    const float* user_emb   = (const float*)d_in[0];  // [100000, 64]
    const float* entity_emb = (const float*)d_in[1];  // [50000, 64]
    const int*   rows       = (const int*)d_in[2];    // [NNZ]
    const int*   cols       = (const int*)d_in[3];    // [NNZ]
    const float* vals       = (const float*)d_in[4];  // [NNZ]
    int nnz = in_sizes[2];

    int n_entities = in_sizes[1] / DIM;  // 50000

    float* entity_agg = (float*)d_out;                         // [50000, 64]
    float* user_agg   = (float*)d_out + (size_t)n_entities * DIM;  // [100000, 64]

    // Harness poisons d_out with 0xAA; we accumulate via atomics, so zero it.
    hipMemsetAsync(d_out, 0, (size_t)out_size * sizeof(float), stream);

    long long total = (long long)nnz * DIM;
    int block = 256;
    long long grid = (total + block - 1) / block;
    coo_scatter_kernel<<<(int)grid, block, 0, stream>>>(
        user_emb, entity_emb, rows, cols, vals, entity_agg, user_agg, nnz);
}